// Round 2
// baseline (843.101 us; speedup 1.0000x reference)
//
#include <hip/hip_runtime.h>
#include <hip/hip_bf16.h>

// ModulatedConv2d: B=16, Cin=Cout=512, H=W=64, 3x3, pad 1.
// out[b,o] = dscale[b,o] * conv2d(s[b,:]*x[b], weight)   (weights shared across batch)

constexpr float CONV_SCALE = 0.014731391274719738f;  // 1/sqrt(512*9)
constexpr float MOD_SCALE  = 0.04419417382415922f;   // 1/sqrt(512)

typedef short  bf16x8 __attribute__((ext_vector_type(8)));
typedef float  f32x4  __attribute__((ext_vector_type(4)));

__device__ __forceinline__ unsigned short f2bf(float f) {
  unsigned u = __float_as_uint(f);
  u += 0x7fffu + ((u >> 16) & 1u);           // round-to-nearest-even
  return (unsigned short)(u >> 16);
}

__device__ __forceinline__ void async16(const void* g, void* l) {
  __builtin_amdgcn_global_load_lds((const __attribute__((address_space(1))) unsigned int*)g,
                                   (__attribute__((address_space(3))) unsigned int*)l,
                                   16, 0, 0);
}

// ---------- kernel 1: s[b,i] = style[b,:] . mod_weight[i,:] * MOD_SCALE + mod_bias[i] ----------
__global__ void k_style(const float* __restrict__ style, const float* __restrict__ mw,
                        const float* __restrict__ mb, float* __restrict__ s) {
  int t = blockIdx.x * 256 + threadIdx.x;    // 8192 threads
  int b = t & 15, i = t >> 4;
  const float4* st = (const float4*)(style + b * 512);
  const float4* wr = (const float4*)(mw + i * 512);
  float acc = 0.f;
#pragma unroll 8
  for (int j = 0; j < 128; ++j) {
    float4 a = st[j], w4 = wr[j];
    acc += a.x * w4.x + a.y * w4.y + a.z * w4.z + a.w * w4.w;
  }
  s[b * 512 + i] = acc * MOD_SCALE + mb[i];
}

// ---------- kernel 2: wsq[o,i] = sum_taps w^2 ; wt[kh][kw][o][ic] = bf16(w) ----------
__global__ void k_prepw(const float* __restrict__ w, float* __restrict__ wsq,
                        unsigned short* __restrict__ wt) {
  __shared__ float Wl[2304];
  int t = threadIdx.x;
  size_t base = (size_t)blockIdx.x * 2304;
#pragma unroll
  for (int k = 0; k < 3; ++k) {
    int idx = t + k * 256;
    if (idx < 576) ((float4*)Wl)[idx] = ((const float4*)(w + base))[idx];
  }
  __syncthreads();
  int g = blockIdx.x * 256 + t;
  int ic = g & 511, o = g >> 9;
  float ssq = 0.f;
#pragma unroll
  for (int tap = 0; tap < 9; ++tap) {
    float v = Wl[t * 9 + tap];
    ssq += v * v;
    wt[((size_t)tap * 512 + o) * 512 + ic] = f2bf(v);
  }
  wsq[o * 512 + ic] = ssq;
}

// ---------- kernel 3: dscale[b,o] = rsqrt(CS^2 * sum_i wsq[o,i]*s[b,i]^2 + 1e-8) * CS ----------
__global__ void k_dscale(const float* __restrict__ s, const float* __restrict__ wsq,
                         float* __restrict__ dscale) {
  int t = blockIdx.x * 256 + threadIdx.x;    // 8192 threads
  int b = t & 15, o = t >> 4;
  const float4* sq = (const float4*)(wsq + o * 512);
  const float4* sb = (const float4*)(s + b * 512);
  float acc = 0.f;
#pragma unroll 8
  for (int j = 0; j < 128; ++j) {
    float4 q4 = sq[j], s4 = sb[j];
    acc += q4.x * s4.x * s4.x + q4.y * s4.y * s4.y + q4.z * s4.z * s4.z + q4.w * s4.w * s4.w;
  }
  float d = rsqrtf(CONV_SCALE * CONV_SCALE * acc + 1e-8f);
  dscale[b * 512 + o] = d * CONV_SCALE;
}

// ---------- kernel 3b: zero the two padded halo rows (hp=0 and hp=65) of xt for each b ----------
__global__ void k_zpad(unsigned short* __restrict__ xt) {
  int strip = blockIdx.x;                    // 32 strips: 16 b x {row 0, row 65}
  int b = strip >> 1, sel = strip & 1;
  unsigned short* p = xt + ((size_t)(b * 66 + sel * 65) * 64) * 512;
  int4 z = {0, 0, 0, 0};
  for (int idx = threadIdx.x; idx < 4096; idx += 256)   // 64*512 bf16 = 65536 B
    ((int4*)p)[idx] = z;
}

// ---------- kernel 4: xt[b][h+1][w][ic] = bf16(x[b][ic][h][w] * s[b][ic])  (NCHW->NHWC) ----------
// LDS-FREE transpose: each thread loads 8 adjacent-ic rows (float4 of 4 w, perfectly coalesced
// per row: 16 lanes x 16B = 256B contiguous), packs the 8-ic bf16 octet IN REGISTERS, stores
// uint4 direct. Replaces the previous per-element scalar ds_read_b32 gather (~131K reads/CU).
__global__ void k_xt(const float* __restrict__ x, const float* __restrict__ s,
                     unsigned short* __restrict__ xt) {
  int h = blockIdx.x, b = blockIdx.y;
  const float* xp = x + (size_t)b * 512 * 4096 + h * 64;
  unsigned short* xo = xt + ((size_t)(b * 66 + h + 1) * 64) * 512;
  int t = threadIdx.x;
  int o8 = t >> 4, wq = t & 15;              // ic-octet (0..15), w-quad (0..15)
  for (int ic0 = 0; ic0 < 512; ic0 += 128) {
    int icb = ic0 + o8 * 8;
    float4 v[8];
    float sc[8];
#pragma unroll
    for (int r = 0; r < 8; ++r) {
      v[r] = *(const float4*)&xp[(size_t)(icb + r) * 4096 + wq * 4];
      sc[r] = s[b * 512 + icb + r];
    }
#pragma unroll
    for (int j = 0; j < 4; ++j) {            // 4 w-values of this quad
      unsigned pk[4];
#pragma unroll
      for (int p = 0; p < 4; ++p) {
        float lo = ((const float*)&v[2 * p])[j]     * sc[2 * p];
        float hi = ((const float*)&v[2 * p + 1])[j] * sc[2 * p + 1];
        pk[p] = (unsigned)f2bf(lo) | ((unsigned)f2bf(hi) << 16);
      }
      *(uint4*)&xo[(size_t)(wq * 4 + j) * 512 + icb] = *(uint4*)pk;
    }
  }
}

// ---------- kernel 5: the conv (implicit GEMM, MFMA bf16, 3-barrier counted-vmcnt pipeline) ----
// grid 512 blocks (1D, XCD-decoded); block 256 = 4 waves; 1 wave/SIMD (acc[8][8] = 256 AGPR).
// Block tile: 128 o x (8 rows x 64 cols).  Wave: 128 o x 2 rows -> 8x8 frags of 16x16:
// 48 ds_read_b128 per 192 MFMAs (vs 36/96 before) -> LDS pipe 2304 cy < MFMA 3072 cy per phase.
// Buffers: Xs double (per ic-step), Wb triple (per kh) -> every stage has 2-phase lead time,
// ONE barrier per phase.  Per-wave stage loads: X=10, W=6.  vmcnt FIFO (steady state):
//   end ph0: queue [W(i,1)* | W(i,2):6, X(i+1):10] need W(i,1)   -> vmcnt(16)
//   end ph1: queue [W(i,2):6 | X(i+1):10, W(i+1,0):6] need W(i,2) -> vmcnt(16)
//   end ph2: queue [X(i+1):10, W(i+1,0):6 | W(i+1,1):6] need both -> vmcnt(6)
// LDS chunk-swizzle (16B chunk q of 64B row at q ^ ((col>>1)&3)): linear gload_lds dest +
// XOR'd GLOBAL source + same XOR on ds_read side (rule 21; verified 0 conflicts in round 1).
__global__ __launch_bounds__(256, 1)
void k_conv(const unsigned short* __restrict__ xt, const unsigned short* __restrict__ wt,
            const float* __restrict__ dscale, float* __restrict__ out) {
  __shared__ short Xs[2][10 * 66 * 32];   // 2 x 41.25 KB: [row(8+2 halo)][col(pad+64+pad)][ic32]
  __shared__ short Wb[3][3 * 128 * 32];   // 3 x 24 KB:    per-kh [kw][o128][ic32]

  // XCD-aware decode: XCD k (= lin%8, round-robin dispatch) owns o-slice k>>1 -> W slice
  // (1.18 MB) is L2-resident per XCD; 8 b x 8 h-tiles fill the rest.  Bijective for 512 blocks.
  const int lin = blockIdx.x;
  const int k8 = lin & 7, jj = lin >> 3;
  const int o0 = (k8 >> 1) * 128;
  const int b  = ((k8 & 1) << 3) | (jj >> 3);
  const int h0 = (jj & 7) * 8;
  const int t = threadIdx.x;
  const int wave = t >> 6, lane = t & 63;
  const int q = lane >> 4, l16 = lane & 15;

  const int xsrc8 = ((lane & 3) ^ ((((lane >> 2) + 1) >> 1) & 3)) * 8;
  const int wsrc8 = ((lane & 3) ^ ((lane >> 3) & 3)) * 8;
  const int wq8 = (q ^ ((l16 >> 1) & 3)) * 8;

  f32x4 acc[8][8];
#pragma unroll
  for (int i = 0; i < 8; ++i)
#pragma unroll
    for (int j = 0; j < 8; ++j) acc[i][j] = (f32x4){0.f, 0.f, 0.f, 0.f};

  // zero halo columns (col 0 and 65) of all 10 rows, BOTH X buffers (whole 64B col-rows ->
  // swizzle-invariant: any chunk permutation of zeros is zeros)
  for (int z = t; z < 640; z += 256) {
    int bi = (z >= 320) ? 1 : 0;
    int zz = z - bi * 320;
    int r = zz >> 5, rem = zz & 31;
    int col = (rem >> 4) * 65, ch2 = (rem & 15) * 2;
    *(int*)&Xs[bi][(r * 66 + col) * 32 + ch2] = 0;
  }

  auto stageX = [&](int i_, int xb_) {
    int ic0_ = i_ * 32;
#pragma unroll
    for (int j2 = 0; j2 < 10; ++j2) {
      int c = wave * 10 + j2;               // 40 chunks: 10 rows x 4 col-quarters
      int row = c >> 2, q16 = c & 3;
      async16(xt + ((size_t)((b * 66 + h0 + row) * 64) + q16 * 16 + (lane >> 2)) * 512 + ic0_ + xsrc8,
              &Xs[xb_][(row * 66 + 1 + q16 * 16) * 32]);
    }
  };
  auto stageW = [&](int i_, int kh_, int wb_) {
    int ic0_ = i_ * 32;
#pragma unroll
    for (int j2 = 0; j2 < 6; ++j2) {
      int ci = wave * 6 + j2;               // 24 chunks: 3 kw x 8 o-groups
      int kw = ci >> 3, oo = ((ci & 7) << 4) + (lane >> 2);
      async16(wt + (((size_t)(kh_ * 3 + kw) * 512 + o0 + oo) * 512 + ic0_ + wsrc8),
              &Wb[wb_][ci * 512]);
    }
  };
  auto compute = [&](int kh, int cur) {
    __builtin_amdgcn_s_setprio(1);
#pragma unroll
    for (int kw = 0; kw < 3; ++kw) {
      bf16x8 bfr[8];
#pragma unroll
      for (int rr = 0; rr < 2; ++rr)
#pragma unroll
        for (int ni = 0; ni < 4; ++ni) {
          int c = ni * 16 + l16 + kw;
          bfr[rr * 4 + ni] = *(const bf16x8*)
              &Xs[cur][((2 * wave + kh + rr) * 66 + c) * 32 + ((q ^ ((c >> 1) & 3)) << 3)];
        }
#pragma unroll
      for (int mi = 0; mi < 8; ++mi) {
        bf16x8 af = *(const bf16x8*)&Wb[kh][(kw * 128 + mi * 16 + l16) * 32 + wq8];
#pragma unroll
        for (int nj = 0; nj < 8; ++nj)
          acc[mi][nj] = __builtin_amdgcn_mfma_f32_16x16x32_bf16(af, bfr[nj], acc[mi][nj], 0, 0, 0);
      }
    }
    __builtin_amdgcn_s_setprio(0);
  };

  // prologue: X(0), W(0,0), W(0,1); full drain once (also covers halo ds_writes).
  stageX(0, 0);
  stageW(0, 0, 0);
  stageW(0, 1, 1);
  __syncthreads();

#pragma unroll 2
  for (int i = 0; i < 16; ++i) {
    const int cur = i & 1;
    const int inx = (i < 15) ? i + 1 : 15;   // tail: dummy re-stage (freed buffers, never read)
    // ---- phase 0 (kh=0): reads Xs[cur], Wb[0]
    stageW(i, 2, 2);                         // W(i,2): used this step, 2 phases ahead
    stageX(inx, cur ^ 1);                    // X(i+1): used next step
    compute(0, cur);
    asm volatile("s_waitcnt vmcnt(16)" ::: "memory");   // W(i,1) landed
    __builtin_amdgcn_s_barrier();
    // ---- phase 1 (kh=1): reads Wb[1]
    stageW(inx, 0, 0);                       // W(i+1,0): Wb[0] freed by barrier above
    compute(1, cur);
    asm volatile("s_waitcnt vmcnt(16)" ::: "memory");   // W(i,2) landed
    __builtin_amdgcn_s_barrier();
    // ---- phase 2 (kh=2): reads Wb[2]
    stageW(inx, 1, 1);                       // W(i+1,1): Wb[1] freed
    compute(2, cur);
    asm volatile("s_waitcnt vmcnt(6)" ::: "memory");    // X(i+1) + W(i+1,0) landed
    __builtin_amdgcn_s_barrier();
  }
  asm volatile("s_waitcnt vmcnt(0)" ::: "memory");      // drain tail dummies

  // ---- epilogue: D[row=q*4+r][col=l16] per 16x16 frag; scale by dscale[b,o]
#pragma unroll
  for (int mi = 0; mi < 8; ++mi)
#pragma unroll
    for (int r = 0; r < 4; ++r) {
      int o_l = mi * 16 + q * 4 + r;
      float ds = dscale[b * 512 + o0 + o_l];
#pragma unroll
      for (int rr = 0; rr < 2; ++rr) {
        int h = h0 + 2 * wave + rr;
        float* orow = out + ((size_t)(b * 512 + o0 + o_l) * 64 + h) * 64;
#pragma unroll
        for (int ni = 0; ni < 4; ++ni)
          orow[ni * 16 + l16] = acc[mi][rr * 4 + ni][r] * ds;
      }
    }
}

extern "C" void kernel_launch(void* const* d_in, const int* in_sizes, int n_in,
                              void* d_out, int out_size, void* d_ws, size_t ws_size,
                              hipStream_t stream) {
  const float* x      = (const float*)d_in[0];  // (16,512,64,64)
  const float* style  = (const float*)d_in[1];  // (16,512)
  const float* weight = (const float*)d_in[2];  // (1,512,512,3,3)
  const float* mw     = (const float*)d_in[3];  // (512,512)
  const float* mb     = (const float*)d_in[4];  // (512,)
  float* out = (float*)d_out;

  // workspace layout
  float* s      = (float*)d_ws;                       // 8192 f32
  float* dscale = s + 8192;                           // 8192 f32
  float* wsq    = dscale + 8192;                      // 262144 f32
  unsigned short* wt = (unsigned short*)(wsq + 262144);  // 9*512*512 bf16 = 4.5 MiB
  unsigned short* xt = wt + 9 * 512 * 512;            // 16*66*64*512 bf16 = 66 MiB (2 halo rows/b)

  k_style<<<32, 256, 0, stream>>>(style, mw, mb, s);
  k_prepw<<<1024, 256, 0, stream>>>(weight, wsq, wt);
  k_dscale<<<32, 256, 0, stream>>>(s, wsq, dscale);
  k_zpad<<<32, 256, 0, stream>>>(xt);
  k_xt<<<dim3(64, 16), 256, 0, stream>>>(x, s, xt);
  k_conv<<<512, 256, 0, stream>>>(xt, wt, dscale, out);
}

// Round 5
// 528.626 us; speedup vs baseline: 1.5949x; 1.5949x over previous
//
#include <hip/hip_runtime.h>
#include <hip/hip_bf16.h>

// ModulatedConv2d: B=16, Cin=Cout=512, H=W=64, 3x3, pad 1.
// out[b,o] = dscale[b,o] * conv2d(s[b,:]*x[b], weight)   (weights shared across batch)

constexpr float CONV_SCALE = 0.014731391274719738f;  // 1/sqrt(512*9)
constexpr float MOD_SCALE  = 0.04419417382415922f;   // 1/sqrt(512)

typedef short  bf16x8 __attribute__((ext_vector_type(8)));
typedef float  f32x4  __attribute__((ext_vector_type(4)));

__device__ __forceinline__ unsigned short f2bf(float f) {
  unsigned u = __float_as_uint(f);
  u += 0x7fffu + ((u >> 16) & 1u);           // round-to-nearest-even
  return (unsigned short)(u >> 16);
}

__device__ __forceinline__ void async16(const void* g, void* l) {
  __builtin_amdgcn_global_load_lds((const __attribute__((address_space(1))) unsigned int*)g,
                                   (__attribute__((address_space(3))) unsigned int*)l,
                                   16, 0, 0);
}

// ---------- kernel 1: s[b,i] = style[b,:] . mod_weight[i,:] * MOD_SCALE + mod_bias[i] ----------
__global__ void k_style(const float* __restrict__ style, const float* __restrict__ mw,
                        const float* __restrict__ mb, float* __restrict__ s) {
  int t = blockIdx.x * 256 + threadIdx.x;    // 8192 threads
  int b = t & 15, i = t >> 4;
  const float4* st = (const float4*)(style + b * 512);
  const float4* wr = (const float4*)(mw + i * 512);
  float acc = 0.f;
#pragma unroll 8
  for (int j = 0; j < 128; ++j) {
    float4 a = st[j], w4 = wr[j];
    acc += a.x * w4.x + a.y * w4.y + a.z * w4.z + a.w * w4.w;
  }
  s[b * 512 + i] = acc * MOD_SCALE + mb[i];
}

// ---------- kernel 2: wsq[o,i] = sum_taps w^2 ; wt[kh][kw][o][ic] = bf16(w) ----------
__global__ void k_prepw(const float* __restrict__ w, float* __restrict__ wsq,
                        unsigned short* __restrict__ wt) {
  __shared__ float Wl[2304];
  int t = threadIdx.x;
  size_t base = (size_t)blockIdx.x * 2304;
#pragma unroll
  for (int k = 0; k < 3; ++k) {
    int idx = t + k * 256;
    if (idx < 576) ((float4*)Wl)[idx] = ((const float4*)(w + base))[idx];
  }
  __syncthreads();
  int g = blockIdx.x * 256 + t;
  int ic = g & 511, o = g >> 9;
  float ssq = 0.f;
#pragma unroll
  for (int tap = 0; tap < 9; ++tap) {
    float v = Wl[t * 9 + tap];
    ssq += v * v;
    wt[((size_t)tap * 512 + o) * 512 + ic] = f2bf(v);
  }
  wsq[o * 512 + ic] = ssq;
}

// ---------- kernel 3: dscale[b,o] = rsqrt(CS^2 * sum_i wsq[o,i]*s[b,i]^2 + 1e-8) * CS ----------
__global__ void k_dscale(const float* __restrict__ s, const float* __restrict__ wsq,
                         float* __restrict__ dscale) {
  int t = blockIdx.x * 256 + threadIdx.x;    // 8192 threads
  int b = t & 15, o = t >> 4;
  const float4* sq = (const float4*)(wsq + o * 512);
  const float4* sb = (const float4*)(s + b * 512);
  float acc = 0.f;
#pragma unroll 8
  for (int j = 0; j < 128; ++j) {
    float4 q4 = sq[j], s4 = sb[j];
    acc += q4.x * s4.x * s4.x + q4.y * s4.y * s4.y + q4.z * s4.z * s4.z + q4.w * s4.w * s4.w;
  }
  float d = rsqrtf(CONV_SCALE * CONV_SCALE * acc + 1e-8f);
  dscale[b * 512 + o] = d * CONV_SCALE;
}

// ---------- kernel 3b: zero the two padded halo rows (hp=0 and hp=65) of xt for each b ----------
__global__ void k_zpad(unsigned short* __restrict__ xt) {
  int strip = blockIdx.x;                    // 32 strips: 16 b x {row 0, row 65}
  int b = strip >> 1, sel = strip & 1;
  unsigned short* p = xt + ((size_t)(b * 66 + sel * 65) * 64) * 512;
  int4 z = {0, 0, 0, 0};
  for (int idx = threadIdx.x; idx < 4096; idx += 256)   // 64*512 bf16 = 65536 B
    ((int4*)p)[idx] = z;
}

// ---------- kernel 4: xt[b][h+1][w][ic] = bf16(x[b][ic][h][w] * s[b][ic])  (NCHW->NHWC) ----------
// LDS-FREE transpose: each thread loads 8 adjacent-ic rows (float4 of 4 w, coalesced per row),
// packs the 8-ic bf16 octet IN REGISTERS, stores uint4 direct. (Proven correct, round 2.)
__global__ void k_xt(const float* __restrict__ x, const float* __restrict__ s,
                     unsigned short* __restrict__ xt) {
  int h = blockIdx.x, b = blockIdx.y;
  const float* xp = x + (size_t)b * 512 * 4096 + h * 64;
  unsigned short* xo = xt + ((size_t)(b * 66 + h + 1) * 64) * 512;
  int t = threadIdx.x;
  int o8 = t >> 4, wq = t & 15;              // ic-octet (0..15), w-quad (0..15)
  for (int ic0 = 0; ic0 < 512; ic0 += 128) {
    int icb = ic0 + o8 * 8;
    float4 v[8];
    float sc[8];
#pragma unroll
    for (int r = 0; r < 8; ++r) {
      v[r] = *(const float4*)&xp[(size_t)(icb + r) * 4096 + wq * 4];
      sc[r] = s[b * 512 + icb + r];
    }
#pragma unroll
    for (int j = 0; j < 4; ++j) {            // 4 w-values of this quad
      unsigned pk[4];
#pragma unroll
      for (int p = 0; p < 4; ++p) {
        float lo = ((const float*)&v[2 * p])[j]     * sc[2 * p];
        float hi = ((const float*)&v[2 * p + 1])[j] * sc[2 * p + 1];
        pk[p] = (unsigned)f2bf(lo) | ((unsigned)f2bf(hi) << 16);
      }
      *(uint4*)&xo[(size_t)(wq * 4 + j) * 512 + icb] = *(uint4*)pk;
    }
  }
}

// ---------- kernel 5: the conv (implicit GEMM, MFMA bf16, de-phased waves) ----------
// REVERT to the proven round-1 geometry (8 waves x (128o x 1 row), acc[8][4]=128 VGPR,
// INTRINSIC MFMA — the asm-MFMA branch was falsified in rounds 3-4) and fix round-1's
// measured serialization instead: round-1's per-phase barriers aligned all 8 waves ->
// LDS pipe (3456cy) and MFMA pipe (3725cy) ran back-to-back (7065cy/phase measured).
// NEW: the ONLY intra-step sync is one vmcnt+barrier after W staging; all 3 kh phases
// run fence-free so waves naturally de-phase and LDS reads of one wave overlap MFMAs
// of another.  Buffers: W holds the FULL step (9 planes, 73.7KB, single); X double
// (2x41.25KB, prefetched one full step ahead).  LDS = 158,208 B (same as rounds 2-4).
// Per step:  stageW(i):9/wave; stageX(i+1):5/wave; vmcnt(5) certifies own W chunks;
// s_barrier certifies all waves' W; compute kh=0,1,2; __syncthreads() (vmcnt0+lgkmcnt0)
// certifies X(i+1) cross-wave for next step AND closes the W-overwrite race (all ds_reads
// of W(i) complete before any wave can issue stageW(i+1)).  The end-of-step drain is free:
// X(i+1) was issued ~9000cy earlier.  The W wait (~250-600cy, L2-warm after block-round 1)
// is the only exposed latency.
// LDS chunk-swizzle as rounds 0-1 (0 conflicts verified): linear gload_lds dest + XOR'd
// global source + same XOR on the ds_read side.
__global__ __launch_bounds__(512, 2)
void k_conv(const unsigned short* __restrict__ xt, const unsigned short* __restrict__ wt,
            const float* __restrict__ dscale, float* __restrict__ out) {
  __shared__ short Xs[2][10 * 66 * 32];   // 2 x 41.25 KB: [row(8+2 halo)][col(pad+64+pad)][ic32]
  __shared__ short Wf[9 * 128 * 32];      // 73.7 KB: [plane=kh*3+kw][o128][ic32]

  // XCD-aware decode: XCD k (= lin%8, round-robin dispatch) owns o-slice k>>1 -> its W slice
  // (1.18 MB) stays L2-resident.  Bijective for 512 blocks.
  const int lin = blockIdx.x;
  const int k8 = lin & 7, jj = lin >> 3;
  const int o0 = (k8 >> 1) * 128;
  const int b  = ((k8 & 1) << 3) | (jj >> 3);
  const int h0 = (jj & 7) * 8;
  const int t = threadIdx.x;
  const int wave = t >> 6, lane = t & 63;
  const int q = lane >> 4, l16 = lane & 15;

  const int xsrc8 = ((lane & 3) ^ ((((lane >> 2) + 1) >> 1) & 3)) * 8;
  const int wsrc8 = ((lane & 3) ^ ((lane >> 3) & 3)) * 8;
  const int wq8 = (q ^ ((l16 >> 1) & 3)) * 8;

  f32x4 acc[8][4];
#pragma unroll
  for (int i = 0; i < 8; ++i)
#pragma unroll
    for (int j = 0; j < 4; ++j) acc[i][j] = (f32x4){0.f, 0.f, 0.f, 0.f};

  // zero halo columns (col 0 and 65) of all 10 rows, BOTH X buffers (whole 64B col-rows ->
  // swizzle-invariant: any chunk permutation of zeros is zeros)
  for (int z = t; z < 640; z += 512) {
    int bi = (z >= 320) ? 1 : 0;
    int zz = z - bi * 320;
    int r = zz >> 5, rem = zz & 31;
    int col = (rem >> 4) * 65, ch2 = (rem & 15) * 2;
    *(int*)&Xs[bi][(r * 66 + col) * 32 + ch2] = 0;
  }

  auto stageX = [&](int i_, int xb_) {
    int ic0_ = i_ * 32;
#pragma unroll
    for (int j2 = 0; j2 < 5; ++j2) {
      int c = wave * 5 + j2;                // 40 chunks: 10 rows x 4 col-quarters
      int row = c >> 2, q16 = c & 3;
      async16(xt + ((size_t)((b * 66 + h0 + row) * 64) + q16 * 16 + (lane >> 2)) * 512 + ic0_ + xsrc8,
              &Xs[xb_][(row * 66 + 1 + q16 * 16) * 32]);
    }
  };
  auto stageW = [&](int i_) {
    int ic0_ = i_ * 32;
#pragma unroll
    for (int j2 = 0; j2 < 9; ++j2) {
      int ci = wave * 9 + j2;               // 72 chunks: 9 planes x 8 o-groups
      int plane = ci >> 3, oo = ((ci & 7) << 4) + (lane >> 2);
      async16(wt + (((size_t)plane * 512 + o0 + oo) * 512 + ic0_ + wsrc8),
              &Wf[ci * 512]);
    }
  };
  auto compute = [&](int kh, int cur) {
    const short* Xrow = &Xs[cur][(wave + kh) * 66 * 32];
    __builtin_amdgcn_s_setprio(1);
#pragma unroll
    for (int kw = 0; kw < 3; ++kw) {
      bf16x8 bfr[4];
#pragma unroll
      for (int ni = 0; ni < 4; ++ni) {
        int c = ni * 16 + l16 + kw;
        bfr[ni] = *(const bf16x8*)&Xrow[c * 32 + ((q ^ ((c >> 1) & 3)) << 3)];
      }
#pragma unroll
      for (int mi = 0; mi < 8; ++mi) {
        bf16x8 af = *(const bf16x8*)&Wf[((kh * 3 + kw) * 128 + mi * 16 + l16) * 32 + wq8];
#pragma unroll
        for (int ni = 0; ni < 4; ++ni)
          acc[mi][ni] = __builtin_amdgcn_mfma_f32_16x16x32_bf16(af, bfr[ni], acc[mi][ni], 0, 0, 0);
      }
    }
    __builtin_amdgcn_s_setprio(0);
  };

  // prologue: X(0) into buffer 0; full drain (also makes the halo ds_writes visible).
  stageX(0, 0);
  __syncthreads();

  for (int i = 0; i < 16; ++i) {
    const int cur = i & 1;
    stageW(i);                               // W(i): needed THIS step (exposed wait below)
    if (i < 15) {
      stageX(i + 1, cur ^ 1);                // X(i+1): prefetch, certified by step-end drain
      asm volatile("s_waitcnt vmcnt(5)" ::: "memory");   // own 9 W chunks landed; X may fly
    } else {
      asm volatile("s_waitcnt vmcnt(0)" ::: "memory");   // tail: only W outstanding
    }
    __builtin_amdgcn_s_barrier();            // all waves' W chunks certified
    compute(0, cur);                         // no fences between phases: waves de-phase,
    compute(1, cur);                         // LDS reads overlap other waves' MFMAs
    compute(2, cur);
    __syncthreads();                         // vmcnt0+lgkmcnt0+barrier: certifies X(i+1),
  }                                          // frees Wf (all ds_reads of W(i) complete)

  // ---- epilogue: D[row=q*4+r][col=l16] per 16x16 frag; scale by dscale[b,o]
  const int h = h0 + wave;
#pragma unroll
  for (int mi = 0; mi < 8; ++mi)
#pragma unroll
    for (int r = 0; r < 4; ++r) {
      int o_l = mi * 16 + q * 4 + r;
      float ds = dscale[b * 512 + o0 + o_l];
      float* orow = out + ((size_t)(b * 512 + o0 + o_l) * 64 + h) * 64;
#pragma unroll
      for (int ni = 0; ni < 4; ++ni)
        orow[ni * 16 + l16] = acc[mi][ni][r] * ds;
    }
}

extern "C" void kernel_launch(void* const* d_in, const int* in_sizes, int n_in,
                              void* d_out, int out_size, void* d_ws, size_t ws_size,
                              hipStream_t stream) {
  const float* x      = (const float*)d_in[0];  // (16,512,64,64)
  const float* style  = (const float*)d_in[1];  // (16,512)
  const float* weight = (const float*)d_in[2];  // (1,512,512,3,3)
  const float* mw     = (const float*)d_in[3];  // (512,512)
  const float* mb     = (const float*)d_in[4];  // (512,)
  float* out = (float*)d_out;

  // workspace layout
  float* s      = (float*)d_ws;                       // 8192 f32
  float* dscale = s + 8192;                           // 8192 f32
  float* wsq    = dscale + 8192;                      // 262144 f32
  unsigned short* wt = (unsigned short*)(wsq + 262144);  // 9*512*512 bf16 = 4.5 MiB
  unsigned short* xt = wt + 9 * 512 * 512;            // 16*66*64*512 bf16 = 66 MiB (2 halo rows/b)

  k_style<<<32, 256, 0, stream>>>(style, mw, mb, s);
  k_prepw<<<1024, 256, 0, stream>>>(weight, wsq, wt);
  k_dscale<<<32, 256, 0, stream>>>(s, wsq, dscale);
  k_zpad<<<32, 256, 0, stream>>>(xt);
  k_xt<<<dim3(64, 16), 256, 0, stream>>>(x, s, xt);
  k_conv<<<512, 512, 0, stream>>>(xt, wt, dscale, out);
}